// Round 10
// baseline (90.406 us; speedup 1.0000x reference)
//
#include <hip/hip_runtime.h>
#include <math.h>

#define SELU_SCALE 1.0507009873554805f
#define SELU_ALPHA 1.6732632423543772f

constexpr int CIN  = 3;
constexpr int HH   = 32;
constexpr int WW   = 32;
constexpr int OUTF = 64;
constexpr int XSH  = 18;          // 16 output rows + 2 halo rows
constexpr int XSW  = 34;
constexpr int XSC  = XSH * XSW;   // 612 floats per channel
constexpr int PSTRIDE = 68;       // 64 pooled + 3 csum + 1 pad per (n,half)

typedef _Float16 f16x8 __attribute__((ext_vector_type(8)));
typedef float    f32x4 __attribute__((ext_vector_type(4)));

__device__ __forceinline__ unsigned int pack2(float a, float b) {
    return __builtin_bit_cast(unsigned int, __builtin_amdgcn_cvt_pkrtz(a, b));
}

template <int CTRL, int ROW_MASK>
__device__ __forceinline__ float dpp_add(float v) {
    int sh = __builtin_amdgcn_update_dpp(0, __float_as_int(v),
                                         CTRL, ROW_MASK, 0xf, false);
    return v + __int_as_float(sh);
}
__device__ __forceinline__ float wave64_sum(float v) {
    v = dpp_add<0x111, 0xf>(v);
    v = dpp_add<0x112, 0xf>(v);
    v = dpp_add<0x114, 0xf>(v);
    v = dpp_add<0x118, 0xf>(v);
    v = dpp_add<0x142, 0xa>(v);  // row_bcast:15
    v = dpp_add<0x143, 0xc>(v);  // row_bcast:31
    return v;                    // lane 63 = total
}

__device__ __forceinline__ float selu_ns(float s) {  // SELU without outer scale
    float e = SELU_ALPHA * (__expf(s) - 1.f);
    return s > 0.f ? s : e;
}

// Kernel A: one block per HALF image (2048 blocks => 8 blocks/CU => 32
// waves/CU, the HW max — round-9 diagnosis: grid-limited TLP, dependent
// ds_read->pack->MFMA->exp chains uncovered at 16 waves/CU).
// VGPR budget 64 enforced via __launch_bounds__(256,8); pressure reduced by
// bias-as-A-tap (no C-operand regs), one dd at a time, unroll 1.
// Emits per-(n,half) partials: 64 pooled sums + 3 channel sums -> part[].
__global__ __launch_bounds__(256, 8) void conv_half(
    const float* __restrict__ x,        // (1024, 3, 32, 32)
    const float* __restrict__ weight,   // (27, 64)
    const float* __restrict__ bias,     // (64,)
    float* __restrict__ part)           // (2048, 68)
{
    const int b    = blockIdx.x;        // 0..2047
    const int n    = b >> 1;
    const int h0   = (b & 1) << 4;      // 0 or 16
    const int t    = threadIdx.x;
    const int lane = t & 63;
    const int wv   = t >> 6;
    const int quad = lane >> 4;
    const int m16  = lane & 15;

    __shared__ float xs[CIN * XSC];     // 7.3 KB zero-padded half tile
    __shared__ uint4 wfrag[4][64];      // 4 KB packed B fragments
    __shared__ float red4[4][4][OUTF];  // 4 KB per-(wave,quad) partials
    __shared__ float credu[CIN][4];

    // ---- zero tile (borders) + pack B fragments, one barrier ----
    for (int i = t; i < CIN * XSC; i += 256) xs[i] = 0.f;
    {
        const int ot = t >> 6, ln = t & 63;
        const int oc = ot * 16 + (ln & 15);
        const int k0 = (ln >> 4) * 8;
        unsigned int d[4];
        #pragma unroll
        for (int r = 0; r < 4; ++r) {
            const int ka = k0 + 2 * r, kb = ka + 1;
            const float wa = (ka < 27) ? weight[ka * OUTF + oc]
                                       : (ka == 27 ? bias[oc] : 0.f);
            const float wb = (kb < 27) ? weight[kb * OUTF + oc]
                                       : (kb == 27 ? bias[oc] : 0.f);
            d[r] = pack2(wa, wb);
        }
        wfrag[ot][ln] = make_uint4(d[0], d[1], d[2], d[3]);
    }
    __syncthreads();

    // ---- stage 18 rows (incl. halo) + channel sums over OWN 16 rows ----
    const float* xn = x + (size_t)n * (CIN * HH * WW);
    float cp0 = 0.f, cp1 = 0.f, cp2 = 0.f;
    for (int i = t; i < CIN * XSH * WW; i += 256) {   // 1728 elems
        const int c   = i / 576;          // 576 = 9*64 -> wave-uniform
        const int rc  = i - c * 576;
        const int row = rc >> 5, col = rc & 31;
        const int gr  = h0 - 1 + row;     // global input row, -1..32
        const float v = (gr >= 0 && gr < HH) ? xn[c * 1024 + gr * 32 + col] : 0.f;
        xs[c * XSC + row * XSW + col + 1] = v;
        const float vo = (row >= 1 && row <= 16) ? v : 0.f;   // own rows only
        if (c == 0) cp0 += vo; else if (c == 1) cp1 += vo; else cp2 += vo;
    }
    cp0 = wave64_sum(cp0);
    cp1 = wave64_sum(cp1);
    cp2 = wave64_sum(cp2);
    if (lane == 63) { credu[0][wv] = cp0; credu[1][wv] = cp1; credu[2][wv] = cp2; }
    __syncthreads();

    // ---- B fragments + per-lane tap offsets ----
    f16x8 bfr[4];
    #pragma unroll
    for (int ot = 0; ot < 4; ++ot)
        bfr[ot] = __builtin_bit_cast(f16x8, wfrag[ot][lane]);

    int loff[8];
    #pragma unroll
    for (int j = 0; j < 8; ++j) {
        const int k  = quad * 8 + j;
        const int c  = (k >= 18) ? 2 : (k >= 9 ? 1 : 0);
        const int rm = k - 9 * c;
        const int rr = (rm >= 6) ? 2 : (rm >= 3 ? 1 : 0);
        const int cc = rm - 3 * rr;
        loff[j] = (k < 27) ? (c * XSC + rr * XSW + cc + m16) : m16;
    }
    const bool g3 = (quad == 3);

    // ---- main loop: 8 position-tiles per wave ----
    float racc[4] = {0.f, 0.f, 0.f, 0.f};
    const f32x4 zc = {0.f, 0.f, 0.f, 0.f};
    #pragma unroll 1
    for (int jt = 0; jt < 8; ++jt) {
        const int tile  = wv * 8 + jt;
        const int sbase = (tile >> 1) * XSW + (tile & 1) * 16;

        float v[8];
        #pragma unroll
        for (int j = 0; j < 8; ++j) v[j] = xs[sbase + loff[j]];
        v[3] = g3 ? 1.0f : v[3];   // bias tap (k=27)
        v[4] = g3 ? 0.0f : v[4];   // K-padding (w=0, value don't-care)
        v[5] = g3 ? 0.0f : v[5];
        v[6] = g3 ? 0.0f : v[6];
        v[7] = g3 ? 0.0f : v[7];

        const uint4 au = make_uint4(pack2(v[0], v[1]), pack2(v[2], v[3]),
                                    pack2(v[4], v[5]), pack2(v[6], v[7]));
        const f16x8 af = __builtin_bit_cast(f16x8, au);

        #pragma unroll
        for (int ot = 0; ot < 4; ++ot) {   // one dd at a time: low VGPR
            f32x4 d = __builtin_amdgcn_mfma_f32_16x16x32_f16(af, bfr[ot], zc, 0, 0, 0);
            const float s0 = selu_ns(d[0]);
            const float s1 = selu_ns(d[1]);
            const float s2 = selu_ns(d[2]);
            const float s3 = selu_ns(d[3]);
            racc[ot] += __builtin_amdgcn_sqrtf(fmaf(s0, s0, s1 * s1))
                      + __builtin_amdgcn_sqrtf(fmaf(s2, s2, s3 * s3));
        }
    }

    #pragma unroll
    for (int ot = 0; ot < 4; ++ot)
        red4[wv][quad][ot * 16 + m16] = racc[ot];
    __syncthreads();

    // ---- emit partials ----
    float* pb = part + (size_t)b * PSTRIDE;
    if (t < OUTF) {
        float s = 0.f;
        #pragma unroll
        for (int w = 0; w < 4; ++w)
            #pragma unroll
            for (int q = 0; q < 4; ++q)
                s += red4[w][q][t];
        pb[t] = s;
    } else if (t < OUTF + CIN) {
        const int c = t - OUTF;
        pb[t] = credu[c][0] + credu[c][1] + credu[c][2] + credu[c][3];
    }
}

// Kernel B: combine the two halves, gate, store. 65536 threads.
__global__ __launch_bounds__(256, 4) void gate_store(
    const float* __restrict__ part,         // (2048, 68)
    const float* __restrict__ scale_proj,   // (3, 64)
    const float* __restrict__ scale_bias,   // (64,)
    float* __restrict__ out)                // (1024, 64)
{
    const int gid = blockIdx.x * 256 + threadIdx.x;
    const int n   = gid >> 6;
    const int oc  = gid & 63;
    const float* p0 = part + (size_t)(2 * n) * PSTRIDE;
    const float* p1 = p0 + PSTRIDE;

    const float s    = p0[oc] + p1[oc];
    const float mean = s * (SELU_SCALE / 512.f);   // 32*16 pooled elems
    float g = scale_bias[oc];
    #pragma unroll
    for (int c = 0; c < CIN; ++c) {
        const float cs = (p0[OUTF + c] + p1[OUTF + c]) * (1.f / 1024.f);
        g = fmaf(cs, scale_proj[c * OUTF + oc], g);
    }
    g = 1.f / (1.f + __expf(-g));
    out[gid] = mean * g;
}

extern "C" void kernel_launch(void* const* d_in, const int* in_sizes, int n_in,
                              void* d_out, int out_size, void* d_ws, size_t ws_size,
                              hipStream_t stream) {
    const float* x          = (const float*)d_in[0];
    const float* weight     = (const float*)d_in[1];
    const float* bias       = (const float*)d_in[2];
    const float* scale_proj = (const float*)d_in[3];
    const float* scale_bias = (const float*)d_in[4];
    float* out  = (float*)d_out;
    float* part = (float*)d_ws;   // 2048*68*4 = 557 KB scratch

    conv_half<<<2048, 256, 0, stream>>>(x, weight, bias, part);
    gate_store<<<256, 256, 0, stream>>>(part, scale_proj, scale_bias, out);
}

// Round 11
// 87.486 us; speedup vs baseline: 1.0334x; 1.0334x over previous
//
#include <hip/hip_runtime.h>
#include <math.h>

#define SELU_SCALE 1.0507009873554805f
#define SELU_ALPHA 1.6732632423543772f

constexpr int CIN  = 3;
constexpr int HH   = 32;
constexpr int WW   = 32;
constexpr int OUTF = 64;

typedef _Float16 f16x8 __attribute__((ext_vector_type(8)));
typedef float    f32x4 __attribute__((ext_vector_type(4)));

__device__ __forceinline__ unsigned int pack2(float a, float b) {
    return __builtin_bit_cast(unsigned int, __builtin_amdgcn_cvt_pkrtz(a, b));
}

template <int CTRL, int ROW_MASK>
__device__ __forceinline__ float dpp_add(float v) {
    int sh = __builtin_amdgcn_update_dpp(0, __float_as_int(v),
                                         CTRL, ROW_MASK, 0xf, false);
    return v + __int_as_float(sh);
}
__device__ __forceinline__ float wave64_sum(float v) {
    v = dpp_add<0x111, 0xf>(v);
    v = dpp_add<0x112, 0xf>(v);
    v = dpp_add<0x114, 0xf>(v);
    v = dpp_add<0x118, 0xf>(v);
    v = dpp_add<0x142, 0xa>(v);  // row_bcast:15
    v = dpp_add<0x143, 0xc>(v);  // row_bcast:31
    return v;
}

__device__ __forceinline__ float selu_ns(float s) {  // SELU without outer scale
    const float e = fmaf(__expf(s), SELU_ALPHA, -SELU_ALPHA);
    return s > 0.f ? s : e;
}

// One block per image (round-9 structure — round-10's half-image split showed
// TLP is NOT the limiter; reverted). 4 waves x 16 position-tiles.
// Implicit-GEMM mfma_f32_16x16x32_f16: A = patches, B = weights (k>=27 rows
// zero), C = bias broadcast. C layout: col=lane&15 -> oc, row=quad*4+i ->
// position; LPPool pairs are intra-lane.
// Round-11: manual 1-stage software pipeline — MFMAs of tile jt issue before
// the SELU/sqrt epilogue of tile jt-1, hiding the MFMA-result wait and the
// next ds_read latency under the previous epilogue's ~400 VALU cycles.
__global__ __launch_bounds__(256, 4) void fused_conv_mfma(
    const float* __restrict__ x,            // (1024, 3, 32, 32)
    const float* __restrict__ weight,       // (27, 64)
    const float* __restrict__ bias,         // (64,)
    const float* __restrict__ scale_proj,   // (3, 64)
    const float* __restrict__ scale_bias,   // (64,)
    float* __restrict__ out)                // (1024, 64)
{
    const int n    = blockIdx.x;
    const int t    = threadIdx.x;
    const int lane = t & 63;
    const int wv   = t >> 6;
    const int quad = lane >> 4;
    const int m16  = lane & 15;

    __shared__ float xs[CIN][34][34];   // zero-padded input tile, 13.9 KB
    __shared__ uint4 wfrag[4][64];      // packed B fragments, 4 KB
    __shared__ float red4[4][4][OUTF];  // per-(wave,quad) pooled partials, 4 KB
    __shared__ float credu[CIN][4];

    // ---- zero the padded tile + pack B fragments (one barrier) ----
    float* xsf = &xs[0][0][0];
    for (int i = t; i < CIN * 34 * 34; i += 256) xsf[i] = 0.f;
    {
        const int ot = t >> 6, ln = t & 63;
        const int oc = ot * 16 + (ln & 15);
        const int k0 = (ln >> 4) * 8;
        unsigned int d[4];
        #pragma unroll
        for (int r = 0; r < 4; ++r) {
            const int ka = k0 + 2 * r, kb = ka + 1;
            const float wa = (ka < 27) ? weight[ka * OUTF + oc] : 0.f;
            const float wb = (kb < 27) ? weight[kb * OUTF + oc] : 0.f;
            d[r] = pack2(wa, wb);
        }
        wfrag[ot][ln] = make_uint4(d[0], d[1], d[2], d[3]);
    }
    __syncthreads();

    // ---- load x[n] into LDS interior + per-channel sums ----
    const float* xn = x + (size_t)n * (CIN * HH * WW);
    float cp0 = 0.f, cp1 = 0.f, cp2 = 0.f;
    for (int i = t; i < CIN * HH * WW; i += 256) {
        float v  = xn[i];
        int   c  = i >> 10;
        int   hw = i & 1023;
        xs[c][(hw >> 5) + 1][(hw & 31) + 1] = v;
        if (c == 0) cp0 += v; else if (c == 1) cp1 += v; else cp2 += v;
    }
    cp0 = wave64_sum(cp0);
    cp1 = wave64_sum(cp1);
    cp2 = wave64_sum(cp2);
    if (lane == 63) { credu[0][wv] = cp0; credu[1][wv] = cp1; credu[2][wv] = cp2; }
    __syncthreads();

    // ---- B fragments + bias C operand ----
    f16x8 bfr[4];
    f32x4 cb[4];
    #pragma unroll
    for (int ot = 0; ot < 4; ++ot) {
        bfr[ot] = __builtin_bit_cast(f16x8, wfrag[ot][lane]);
        const float b = bias[ot * 16 + m16];
        cb[ot] = (f32x4){b, b, b, b};
    }

    // ---- per-lane tap offsets (k>=27: any valid addr — weight is 0) ----
    int loff[8];
    #pragma unroll
    for (int j = 0; j < 8; ++j) {
        const int k  = quad * 8 + j;
        const int c  = (k >= 18) ? 2 : (k >= 9 ? 1 : 0);
        const int rm = k - 9 * c;
        const int rr = (rm >= 6) ? 2 : (rm >= 3 ? 1 : 0);
        const int cc = rm - 3 * rr;
        loff[j] = (k < 27) ? (c * 1156 + rr * 34 + cc + m16) : m16;
    }

    // ---- pipelined main loop: MFMA(jt) before epilogue(jt-1) ----
    float racc[4] = {0.f, 0.f, 0.f, 0.f};
    const int tile0 = wv * 16;

    auto load_mfma = [&](int jt, f32x4* dst) {
        const int tile  = tile0 + jt;
        const int sbase = (tile >> 1) * 34 + (tile & 1) * 16;
        float v[8];
        #pragma unroll
        for (int j = 0; j < 8; ++j) v[j] = xsf[sbase + loff[j]];
        const uint4 au = make_uint4(pack2(v[0], v[1]), pack2(v[2], v[3]),
                                    pack2(v[4], v[5]), pack2(v[6], v[7]));
        const f16x8 af = __builtin_bit_cast(f16x8, au);
        #pragma unroll
        for (int ot = 0; ot < 4; ++ot)
            dst[ot] = __builtin_amdgcn_mfma_f32_16x16x32_f16(af, bfr[ot], cb[ot], 0, 0, 0);
    };
    auto epilogue = [&](const f32x4* dd) {
        #pragma unroll
        for (int ot = 0; ot < 4; ++ot) {
            const float s0 = selu_ns(dd[ot][0]);
            const float s1 = selu_ns(dd[ot][1]);
            const float s2 = selu_ns(dd[ot][2]);
            const float s3 = selu_ns(dd[ot][3]);
            racc[ot] += __builtin_amdgcn_sqrtf(fmaf(s0, s0, s1 * s1))
                      + __builtin_amdgcn_sqrtf(fmaf(s2, s2, s3 * s3));
        }
    };

    f32x4 dd[4];
    load_mfma(0, dd);
    #pragma unroll 2
    for (int jt = 1; jt < 16; ++jt) {
        f32x4 nd[4];
        load_mfma(jt, nd);      // in flight while we run the previous epilogue
        epilogue(dd);
        #pragma unroll
        for (int ot = 0; ot < 4; ++ot) dd[ot] = nd[ot];
    }
    epilogue(dd);

    // ---- stash per-(wave,quad) partials ----
    #pragma unroll
    for (int ot = 0; ot < 4; ++ot)
        red4[wv][quad][ot * 16 + m16] = racc[ot];
    __syncthreads();

    // ---- gate + store ----
    if (t < OUTF) {
        float s = 0.f;
        #pragma unroll
        for (int w = 0; w < 4; ++w)
            #pragma unroll
            for (int q = 0; q < 4; ++q)
                s += red4[w][q][t];
        const float mean = s * (SELU_SCALE / 512.f);   // 32*16 pooled elems
        float g = scale_bias[t];
        #pragma unroll
        for (int c = 0; c < CIN; ++c) {
            const float cs = (credu[c][0] + credu[c][1] + credu[c][2] + credu[c][3])
                             * (1.f / 1024.f);
            g = fmaf(cs, scale_proj[c * OUTF + t], g);
        }
        g = 1.f / (1.f + __expf(-g));
        out[(size_t)n * OUTF + t] = mean * g;
    }
}

extern "C" void kernel_launch(void* const* d_in, const int* in_sizes, int n_in,
                              void* d_out, int out_size, void* d_ws, size_t ws_size,
                              hipStream_t stream) {
    const float* x          = (const float*)d_in[0];
    const float* weight     = (const float*)d_in[1];
    const float* bias       = (const float*)d_in[2];
    const float* scale_proj = (const float*)d_in[3];
    const float* scale_bias = (const float*)d_in[4];
    float* out = (float*)d_out;

    fused_conv_mfma<<<1024, 256, 0, stream>>>(x, weight, bias,
                                              scale_proj, scale_bias, out);
}